// Round 2
// baseline (371.301 us; speedup 1.0000x reference)
//
#include <hip/hip_runtime.h>

#define BB 32768
#define BS (BB*16)   // 524288

// ---- ws float offsets ----
#define H0   0       // h0f[16] c0f[16] h0b[16] c0b[16]
#define RECO 64      // rec[16]
#define HFO  128     // final h fwd, B*16 floats
#define HBO  (HFO+BS)

__device__ __forceinline__ float sigm(float x){
    return __builtin_amdgcn_rcpf(1.f + __expf(-x));
}
__device__ __forceinline__ float tanh_f(float x){
    return 1.f - 2.f * __builtin_amdgcn_rcpf(1.f + __expf(2.f * x));
}

struct P29 { const float* p[29]; };
// input indices: 0 values 1 masks 2-4 g_fwd(Wih,Whh,b) 5-7 g_bwd 8 impW 9 impb
// 10 fcW 11 fcb 12-14 dec(Wih,Whh,b) 15 dec_out_W 16 dec_out_b 17 disc_out_W
// 18 disc_out_b 19/20 d_W_0/d_b_0 ... 27/28 d_W_4/d_b_4

// ---------------- prep: init states + batch-invariant decoder scan ----------------
__global__ __launch_bounds__(64) void k_prep(P29 a, float* __restrict__ ws)
{
    int tid = threadIdx.x;
    // initial generator states: x = +/-128, h=c=0 (f gate multiplies c=0 -> dead)
    if (tid < 32) {
        int dir = tid >> 4, u = tid & 15;
        const float* Wih = a.p[2 + 3*dir];
        const float* bia = a.p[4 + 3*dir];
        float s = dir ? -128.f : 128.f;
        float gi = s * Wih[u]      + bia[u];
        float gg = s * Wih[32 + u] + bia[32 + u];
        float go = s * Wih[48 + u] + bia[48 + u];
        float c0 = sigm(gi) * tanh_f(gg);
        float h0 = sigm(go) * tanh_f(c0);
        ws[H0 + dir*32 + u]      = h0;
        ws[H0 + dir*32 + 16 + u] = c0;
    }
    // decoder: batch-invariant -> compute once with 16 lanes
    __shared__ float dh[16], dc[16];
    const float* Wih = a.p[12];
    const float* Whh = a.p[13];
    const float* bb  = a.p[14];
    const float* oW  = a.p[15];
    const float* ob  = a.p[16];
    if (tid < 16) {
        int u = tid;
        float gi = bb[u], gg = bb[32+u], go = bb[48+u];
        #pragma unroll
        for (int k = 0; k < 16; k++) {
            gi += 128.f * Wih[u*16 + k];
            gg += 128.f * Wih[(32+u)*16 + k];
            go += 128.f * Wih[(48+u)*16 + k];
        }
        float c0 = sigm(gi) * tanh_f(gg);
        dc[u] = c0; dh[u] = sigm(go) * tanh_f(c0);
    }
    __syncthreads();
    for (int t = 0; t < 16; t++) {
        float rx[16], rh[16], cold = 0.f;
        if (tid < 16) {
            #pragma unroll
            for (int k = 0; k < 16; k++) { rx[k] = dc[k]; rh[k] = dh[k]; }
            cold = dc[tid];
        }
        __syncthreads();
        if (tid < 16) {
            int u = tid;
            float gi = bb[u], gf = bb[16+u], gg = bb[32+u], go = bb[48+u];
            #pragma unroll
            for (int k = 0; k < 16; k++) {
                gi += rx[k]*Wih[u*16+k]      + rh[k]*Whh[u*16+k];
                gf += rx[k]*Wih[(16+u)*16+k] + rh[k]*Whh[(16+u)*16+k];
                gg += rx[k]*Wih[(32+u)*16+k] + rh[k]*Whh[(32+u)*16+k];
                go += rx[k]*Wih[(48+u)*16+k] + rh[k]*Whh[(48+u)*16+k];
            }
            float cn = sigm(gf)*cold + sigm(gi)*tanh_f(gg);
            dc[u] = cn; dh[u] = sigm(go)*tanh_f(cn);
        }
        __syncthreads();
        if (tid == 0) {
            float o = ob[0];
            #pragma unroll
            for (int k = 0; k < 16; k++) o += dh[k] * oW[k];
            ws[RECO + t] = o;
        }
        __syncthreads();
    }
}

// ---------------- generator LSTM scan: one thread per (b, dir) ----------------
__global__ __launch_bounds__(256) void k_lstm(P29 a, const int* __restrict__ masks,
                                              float* __restrict__ ws)
{
    int dir = (int)(blockIdx.x >= (BB/256));
    int b = blockIdx.x * 256 + threadIdx.x - dir * BB;
    const float* __restrict__ Wih  = a.p[2 + 3*dir];   // [64]
    const float* __restrict__ Whh  = a.p[3 + 3*dir];   // [64][16]
    const float* __restrict__ bia  = a.p[4 + 3*dir];   // [64]
    const float* __restrict__ impW = a.p[8];           // [16]
    const float impb = a.p[9][0];
    float x[16]; unsigned mm = 0;
    {
        const float* vp = a.p[0] + b*16;
        const int* mp = masks + b*16;
        #pragma unroll
        for (int t = 0; t < 16; t++) x[t] = vp[t];
        #pragma unroll
        for (int t = 0; t < 16; t++) mm |= (mp[t] != 0 ? 1u : 0u) << t;
    }
    float h[16], c[16];
    #pragma unroll
    for (int u = 0; u < 16; u++) {
        h[u] = ws[H0 + dir*32 + u];
        c[u] = ws[H0 + dir*32 + 16 + u];
    }
    for (int t = 0; t < 16; t++) {
        float imp = impb;
        #pragma unroll
        for (int k = 0; k < 16; k++) imp += h[k] * impW[k];
        float cc = ((mm >> t) & 1u) ? imp : x[t];
        float g[64];
        #pragma unroll
        for (int j = 0; j < 64; j++) {
            float acc = cc * Wih[j] + bia[j];
            #pragma unroll
            for (int k = 0; k < 16; k++) acc += h[k] * Whh[j*16 + k];
            g[j] = acc;
        }
        #pragma unroll
        for (int u = 0; u < 16; u++) {
            float cn = sigm(g[16+u]) * c[u] + sigm(g[u]) * tanh_f(g[32+u]);
            c[u] = cn;
            h[u] = sigm(g[48+u]) * tanh_f(cn);
        }
    }
    float* o = ws + HFO + (size_t)dir * BS + (size_t)b * 16;
    #pragma unroll
    for (int u = 0; u < 16; u++) o[u] = h[u];
}

// ---------------- per (b,t): imputed, latent, reconstructed, discriminator ----------------
__global__ __launch_bounds__(256) void k_post(P29 a, const int* __restrict__ masks,
                                              const float* __restrict__ ws,
                                              float* __restrict__ out)
{
    int e = blockIdx.x * 256 + threadIdx.x;   // 0..BS-1
    int b = e >> 4, t = e & 15;
    const float* __restrict__ hf = ws + HFO + b*16;
    const float* __restrict__ hb = ws + HBO + b*16;
    float hs[16];
    #pragma unroll
    for (int k = 0; k < 16; k++) hs[k] = hf[k] + hb[k];
    float x = a.p[0][e];
    int m = masks[e];
    float imputed = m ? x : hs[t];
    out[e] = imputed;
    // latent[b][t] = fc_b[t] + hs . fc_W[t,:]
    float lat = a.p[11][t];
    #pragma unroll
    for (int k = 0; k < 16; k++) lat += hs[k] * a.p[10][t*16 + k];
    out[2*BS + e] = lat;
    // reconstructed: batch-invariant broadcast
    out[3*BS + e] = ws[RECO + t];
    // discriminator (f gate dead in every layer: cc = sig(i)*tanh(g))
    const float* W0 = a.p[19]; const float* B0 = a.p[20];
    float a0[32];
    #pragma unroll
    for (int u = 0; u < 32; u++) {   // layer0: 1 -> 32, W(128,1)
        float gi = imputed * W0[u]      + B0[u];
        float gg = imputed * W0[64 + u] + B0[64 + u];
        float go = imputed * W0[96 + u] + B0[96 + u];
        a0[u] = sigm(go) * tanh_f(sigm(gi) * tanh_f(gg));
    }
    const float* W1 = a.p[21]; const float* B1 = a.p[22];
    float a1[16];
    #pragma unroll
    for (int u = 0; u < 16; u++) {   // layer1: 32 -> 16, W(64,32)
        float gi = B1[u], gg = B1[32 + u], go = B1[48 + u];
        #pragma unroll
        for (int k = 0; k < 32; k++) {
            gi += a0[k] * W1[u*32 + k];
            gg += a0[k] * W1[(32+u)*32 + k];
            go += a0[k] * W1[(48+u)*32 + k];
        }
        a1[u] = sigm(go) * tanh_f(sigm(gi) * tanh_f(gg));
    }
    const float* W2 = a.p[23]; const float* B2 = a.p[24];
    float a2[8];
    #pragma unroll
    for (int u = 0; u < 8; u++) {    // layer2: 16 -> 8, W(32,16)
        float gi = B2[u], gg = B2[16 + u], go = B2[24 + u];
        #pragma unroll
        for (int k = 0; k < 16; k++) {
            gi += a1[k] * W2[u*16 + k];
            gg += a1[k] * W2[(16+u)*16 + k];
            go += a1[k] * W2[(24+u)*16 + k];
        }
        a2[u] = sigm(go) * tanh_f(sigm(gi) * tanh_f(gg));
    }
    const float* W3 = a.p[25]; const float* B3 = a.p[26];
    float a3[16];
    #pragma unroll
    for (int u = 0; u < 16; u++) {   // layer3: 8 -> 16, W(64,8)
        float gi = B3[u], gg = B3[32 + u], go = B3[48 + u];
        #pragma unroll
        for (int k = 0; k < 8; k++) {
            gi += a2[k] * W3[u*8 + k];
            gg += a2[k] * W3[(32+u)*8 + k];
            go += a2[k] * W3[(48+u)*8 + k];
        }
        a3[u] = sigm(go) * tanh_f(sigm(gi) * tanh_f(gg));
    }
    const float* W4 = a.p[27]; const float* B4 = a.p[28];
    float a4[32];
    #pragma unroll
    for (int u = 0; u < 32; u++) {   // layer4: 16 -> 32, W(128,16)
        float gi = B4[u], gg = B4[64 + u], go = B4[96 + u];
        #pragma unroll
        for (int k = 0; k < 16; k++) {
            gi += a3[k] * W4[u*16 + k];
            gg += a3[k] * W4[(64+u)*16 + k];
            go += a3[k] * W4[(96+u)*16 + k];
        }
        a4[u] = sigm(go) * tanh_f(sigm(gi) * tanh_f(gg));
    }
    float dout = a.p[18][0];
    #pragma unroll
    for (int k = 0; k < 32; k++) dout += a4[k] * a.p[17][k];
    out[BS + e] = dout;
}

extern "C" void kernel_launch(void* const* d_in, const int* in_sizes, int n_in,
                              void* d_out, int out_size, void* d_ws, size_t ws_size,
                              hipStream_t stream)
{
    float* ws = (float*)d_ws;
    P29 a;
    for (int i = 0; i < 29; i++) a.p[i] = (const float*)d_in[i];
    const int* masks = (const int*)d_in[1];
    k_prep<<<1, 64, 0, stream>>>(a, ws);
    k_lstm<<<(2*BB)/256, 256, 0, stream>>>(a, masks, ws);
    k_post<<<BS/256, 256, 0, stream>>>(a, masks, ws, (float*)d_out);
}